// Round 1
// baseline (385.482 us; speedup 1.0000x reference)
//
#include <hip/hip_runtime.h>
#include <float.h>
#include <math.h>

#define BATCH 4
#define NPTS 4096
#define TT 2048            // target tile size (points); 2 tiles of 24 KB LDS
#define BLK 256
#define H2 (0.03f * 0.03f)
#define RADIUS_C 0.07f
#define EPS_C 1e-12f

// Fused kernel. blockIdx.z selects work type:
//   0: chamfer, query=pred, target=gt   -> accum[0]
//   1: chamfer, query=gt,   target=pred -> accum[0]
//   2: repulsion, query=pred, target=pred (top-4 excl self) -> accum[1]
__global__ __launch_bounds__(BLK) void upsample_loss_kernel(
    const float* __restrict__ pred, const float* __restrict__ gt,
    float* __restrict__ accum)
{
    __shared__ float s[TT * 3];     // 24 KB raw copy of target tile

    const int type = blockIdx.z;
    const int b    = blockIdx.y;
    const int qi   = blockIdx.x * BLK + threadIdx.x;   // query idx within batch

    const float* qbase = (type == 1) ? gt : pred;
    const float* tbase = (type == 0) ? gt : pred;

    const float* q = qbase + ((size_t)b * NPTS + qi) * 3;
    const float qx = q[0], qy = q[1], qz = q[2];

    // m0<=m1<=m2<=m3 smallest d2 (chamfer uses only m0)
    float m0 = FLT_MAX, m1 = FLT_MAX, m2 = FLT_MAX, m3 = FLT_MAX;

    for (int t = 0; t < NPTS / TT; ++t) {
        // cooperative tile load: TT*3 floats as float4 (alignment: tile base
        // offset = (b*4096 + t*2048)*3 floats, multiple of 4 floats)
        const float4* g4 = (const float4*)(tbase + ((size_t)b * NPTS + t * TT) * 3);
        float4* s4 = (float4*)s;
        #pragma unroll
        for (int k = threadIdx.x; k < TT * 3 / 4; k += BLK)
            s4[k] = g4[k];
        __syncthreads();

        if (type < 2) {
            #pragma unroll 4
            for (int jj = 0; jj < TT; ++jj) {
                float dx = qx - s[3 * jj + 0];
                float dy = qy - s[3 * jj + 1];
                float dz = qz - s[3 * jj + 2];
                float d2 = fmaf(dx, dx, fmaf(dy, dy, dz * dz));
                m0 = fminf(m0, d2);
            }
        } else {
            const int jbase = t * TT;
            #pragma unroll 2
            for (int jj = 0; jj < TT; ++jj) {
                float dx = qx - s[3 * jj + 0];
                float dy = qy - s[3 * jj + 1];
                float dz = qz - s[3 * jj + 2];
                float d2 = fmaf(dx, dx, fmaf(dy, dy, dz * dz));
                if (jbase + jj == qi) d2 = FLT_MAX;   // exclude self
                if (d2 < m3) {                        // rare: sorted insert
                    float n0 = fminf(m0, d2);
                    float n1 = fminf(m1, fmaxf(m0, d2));
                    float n2 = fminf(m2, fmaxf(m1, d2));
                    float n3 = fminf(m3, fmaxf(m2, d2));
                    m0 = n0; m1 = n1; m2 = n2; m3 = n3;
                }
            }
        }
        __syncthreads();
    }

    float contrib;
    if (type < 2) {
        contrib = m0;
    } else {
        contrib = 0.0f;
        float ms[4] = {m0, m1, m2, m3};
        #pragma unroll
        for (int k = 0; k < 4; ++k) {
            float d2 = fmaxf(ms[k], EPS_C);
            float d  = sqrtf(d2);
            contrib += (RADIUS_C - d) * expf(-d2 / H2);
        }
    }

    // wave-level reduce (64 lanes), then one atomic per wave
    #pragma unroll
    for (int off = 32; off > 0; off >>= 1)
        contrib += __shfl_down(contrib, off, 64);
    if ((threadIdx.x & 63) == 0)
        atomicAdd(&accum[(type == 2) ? 1 : 0], contrib);
}

__global__ void finalize_kernel(const float* __restrict__ accum,
                                float* __restrict__ out)
{
    if (threadIdx.x == 0) {
        // cd = mean(min pred->gt) + mean(min gt->pred), both over B*N=16384
        out[0] = 100.0f * accum[0] * (1.0f / (BATCH * NPTS));
        // rep = mean over B*N*4
        out[1] = accum[1] * (1.0f / (BATCH * NPTS * 4));
    }
}

extern "C" void kernel_launch(void* const* d_in, const int* in_sizes, int n_in,
                              void* d_out, int out_size, void* d_ws, size_t ws_size,
                              hipStream_t stream)
{
    const float* pred = (const float*)d_in[0];
    const float* gt   = (const float*)d_in[1];
    // d_in[2] = pcd_radius: unused by the reference outputs
    float* accum = (float*)d_ws;

    hipMemsetAsync(accum, 0, 2 * sizeof(float), stream);

    dim3 grid(NPTS / BLK, BATCH, 3);   // 16 x 4 x 3 = 192 blocks
    upsample_loss_kernel<<<grid, BLK, 0, stream>>>(pred, gt, accum);
    finalize_kernel<<<1, 64, 0, stream>>>(accum, (float*)d_out);
}

// Round 2
// 109.699 us; speedup vs baseline: 3.5140x; 3.5140x over previous
//
#include <hip/hip_runtime.h>
#include <float.h>
#include <math.h>

#define BATCH 4
#define NPTS 4096
#define SEG 8
#define TPTS (NPTS / SEG)        // 512 targets per segment -> 6 KB LDS
#define BLK 256
#define H2 (0.03f * 0.03f)
#define RADIUS_C 0.07f
#define EPS_C 1e-12f

// d_ws layout:
//   accum : float[2]                       @ 0
//   minb  : uint[2*BATCH*NPTS] (128 KB)    @ 16        (chamfer per-query min, float bits)
//   top4  : float4[BATCH*NPTS*SEG] (2 MB)  @ 16+131072 (repulsion per-segment top-4)

// blockIdx.z = type*4 + b; type: 0 = pred->gt, 1 = gt->pred, 2 = repulsion (pred->pred)
__global__ __launch_bounds__(BLK) void partial_kernel(
    const float* __restrict__ pred, const float* __restrict__ gt,
    unsigned int* __restrict__ minb, float4* __restrict__ top4)
{
    __shared__ float4 s[TPTS * 3 / 4];      // 384 float4 = 6 KB

    const int z    = blockIdx.z;
    const int type = z >> 2;
    const int b    = z & 3;
    const int seg  = blockIdx.y;
    const int qi   = blockIdx.x * BLK + threadIdx.x;

    const float* qbase = (type == 1) ? gt : pred;
    const float* tbase = (type == 0) ? gt : pred;

    // stage target segment: offset (b*4096 + seg*512)*3 floats is 16B-aligned
    const float4* g4 = (const float4*)(tbase + ((size_t)b * NPTS + seg * TPTS) * 3);
    for (int k = threadIdx.x; k < TPTS * 3 / 4; k += BLK) s[k] = g4[k];
    __syncthreads();

    const float* q = qbase + ((size_t)b * NPTS + qi) * 3;
    const float qx = q[0], qy = q[1], qz = q[2];

    if (type < 2) {
        float m0 = FLT_MAX;
        #pragma unroll 4
        for (int m = 0; m < TPTS / 4; ++m) {
            float4 f0 = s[3 * m + 0], f1 = s[3 * m + 1], f2 = s[3 * m + 2];
            float dx, dy, dz, d2;
            dx = qx - f0.x; dy = qy - f0.y; dz = qz - f0.z;
            d2 = fmaf(dx, dx, fmaf(dy, dy, dz * dz)); m0 = fminf(m0, d2);
            dx = qx - f0.w; dy = qy - f1.x; dz = qz - f1.y;
            d2 = fmaf(dx, dx, fmaf(dy, dy, dz * dz)); m0 = fminf(m0, d2);
            dx = qx - f1.z; dy = qy - f1.w; dz = qz - f2.x;
            d2 = fmaf(dx, dx, fmaf(dy, dy, dz * dz)); m0 = fminf(m0, d2);
            dx = qx - f2.y; dy = qy - f2.z; dz = qz - f2.w;
            d2 = fmaf(dx, dx, fmaf(dy, dy, dz * dz)); m0 = fminf(m0, d2);
        }
        // non-negative floats: bit pattern order == value order
        atomicMin(&minb[((size_t)(type * BATCH + b)) * NPTS + qi], __float_as_uint(m0));
    } else {
        float m0 = FLT_MAX, m1 = FLT_MAX, m2 = FLT_MAX, m3 = FLT_MAX;
        const int base = seg * TPTS;
        #pragma unroll 2
        for (int m = 0; m < TPTS / 4; ++m) {
            float4 f0 = s[3 * m + 0], f1 = s[3 * m + 1], f2 = s[3 * m + 2];
            const float px[4] = {f0.x, f0.w, f1.z, f2.y};
            const float py[4] = {f0.y, f1.x, f1.w, f2.z};
            const float pz[4] = {f0.z, f1.y, f2.x, f2.w};
            #pragma unroll
            for (int k = 0; k < 4; ++k) {
                float dx = qx - px[k], dy = qy - py[k], dz = qz - pz[k];
                float d2 = fmaf(dx, dx, fmaf(dy, dy, dz * dz));
                d2 = (base + 4 * m + k == qi) ? FLT_MAX : d2;   // exclude self
                // branchless sorted top-4 insert
                float n0 = fminf(m0, d2); float t0 = fmaxf(m0, d2);
                float n1 = fminf(m1, t0); float t1 = fmaxf(m1, t0);
                float n2 = fminf(m2, t1); float t2 = fmaxf(m2, t1);
                float n3 = fminf(m3, t2);
                m0 = n0; m1 = n1; m2 = n2; m3 = n3;
            }
        }
        top4[((size_t)b * NPTS + qi) * SEG + seg] = make_float4(m0, m1, m2, m3);
    }
}

// 192 blocks: [0,128) sum chamfer mins; [128,192) merge repulsion top-4s
__global__ __launch_bounds__(BLK) void merge_kernel(
    const unsigned int* __restrict__ minb, const float4* __restrict__ top4,
    float* __restrict__ accum)
{
    float contrib;
    int which;
    if (blockIdx.x < 128) {
        int i = blockIdx.x * BLK + threadIdx.x;          // < 32768
        contrib = __uint_as_float(minb[i]);
        which = 0;
    } else {
        int qi = (blockIdx.x - 128) * BLK + threadIdx.x; // < 16384 (b*NPTS+n)
        const float4* p = &top4[(size_t)qi * SEG];
        float m0 = FLT_MAX, m1 = FLT_MAX, m2 = FLT_MAX, m3 = FLT_MAX;
        #pragma unroll
        for (int sgi = 0; sgi < SEG; ++sgi) {
            float4 v = p[sgi];
            const float vals[4] = {v.x, v.y, v.z, v.w};
            #pragma unroll
            for (int k = 0; k < 4; ++k) {
                float d2 = vals[k];
                float n0 = fminf(m0, d2); float t0 = fmaxf(m0, d2);
                float n1 = fminf(m1, t0); float t1 = fmaxf(m1, t0);
                float n2 = fminf(m2, t1); float t2 = fmaxf(m2, t1);
                float n3 = fminf(m3, t2);
                m0 = n0; m1 = n1; m2 = n2; m3 = n3;
            }
        }
        contrib = 0.0f;
        const float ms[4] = {m0, m1, m2, m3};
        #pragma unroll
        for (int k = 0; k < 4; ++k) {
            float d2 = fmaxf(ms[k], EPS_C);
            float d  = sqrtf(d2);
            contrib += (RADIUS_C - d) * expf(-d2 / H2);
        }
        which = 1;
    }
    #pragma unroll
    for (int off = 32; off > 0; off >>= 1)
        contrib += __shfl_down(contrib, off, 64);
    if ((threadIdx.x & 63) == 0)
        atomicAdd(&accum[which], contrib);
}

__global__ void finalize_kernel(const float* __restrict__ accum,
                                float* __restrict__ out)
{
    if (threadIdx.x == 0) {
        out[0] = 100.0f * accum[0] * (1.0f / (BATCH * NPTS));
        out[1] = accum[1] * (1.0f / (BATCH * NPTS * 4));
    }
}

extern "C" void kernel_launch(void* const* d_in, const int* in_sizes, int n_in,
                              void* d_out, int out_size, void* d_ws, size_t ws_size,
                              hipStream_t stream)
{
    const float* pred = (const float*)d_in[0];
    const float* gt   = (const float*)d_in[1];

    float*        accum = (float*)d_ws;
    unsigned int* minb  = (unsigned int*)((char*)d_ws + 16);
    float4*       top4  = (float4*)((char*)d_ws + 16 + (size_t)2 * BATCH * NPTS * sizeof(unsigned int));

    hipMemsetAsync(accum, 0, 16, stream);
    hipMemsetAsync(minb, 0xFF, (size_t)2 * BATCH * NPTS * sizeof(unsigned int), stream);

    dim3 grid(NPTS / BLK, SEG, 3 * BATCH);   // 16 x 8 x 12 = 1536 blocks
    partial_kernel<<<grid, BLK, 0, stream>>>(pred, gt, minb, top4);
    merge_kernel<<<192, BLK, 0, stream>>>(minb, top4, accum);
    finalize_kernel<<<1, 64, 0, stream>>>(accum, (float*)d_out);
}

// Round 3
// 99.223 us; speedup vs baseline: 3.8850x; 1.1056x over previous
//
#include <hip/hip_runtime.h>
#include <float.h>
#include <math.h>

#define BATCH 4
#define NPTS 4096
#define SEG 8
#define TPTS (NPTS / SEG)        // 512 targets/segment -> 8 KB LDS (float4 w/ |t|^2)
#define BLK 256
#define H2 (0.03f * 0.03f)
#define RADIUS_C 0.07f
#define EPS_C 1e-12f
#define NQ (BATCH * NPTS)        // 16384
#define NCH (2 * NQ)             // 32768 chamfer (type,b,q) rows

// d_ws layout:
//   hdr    : float accum[2] + uint cnt + pad (16 B)     @ 0   (zeroed by partial blk0)
//   minseg : float [SEG][NCH]                (1 MB)     @ 16
//   top4   : float4[SEG][NQ]                 (2 MB)     @ 16 + 1 MB
//
// d2 = (|t|^2 - 2 q.t) + |q|^2  (same expansion as the reference). Inner loops
// track h = |t|^2 - 2 q.t (3 FMA via n = -2q), add |q|^2 at the partial store.

// blockIdx.z = type*4 + b; type: 0 pred->gt, 1 gt->pred, 2 repulsion pred->pred
__global__ __launch_bounds__(BLK) void partial_kernel(
    const float* __restrict__ pred, const float* __restrict__ gt,
    float* __restrict__ minseg, float4* __restrict__ top4,
    unsigned int* __restrict__ hdr)
{
    __shared__ float4 s[TPTS];   // (x, y, z, |t|^2)

    // zero accum[2] + cnt for the merge kernel (visible at kernel boundary)
    if (blockIdx.x == 0 && blockIdx.y == 0 && blockIdx.z == 0 && threadIdx.x < 4)
        hdr[threadIdx.x] = 0u;

    const int type = blockIdx.z >> 2;
    const int b    = blockIdx.z & 3;
    const int seg  = blockIdx.y;
    const int qi   = blockIdx.x * BLK + threadIdx.x;

    const float* qbase = (type == 1) ? gt : pred;
    const float* tbase = (type == 0) ? gt : pred;

    // stage segment: 512 points, 2 per thread, computing |t|^2 on the fly
    {
        const float2* g2 = (const float2*)(tbase + ((size_t)b * NPTS + seg * TPTS) * 3);
        float2 a = g2[3 * threadIdx.x + 0];
        float2 c = g2[3 * threadIdx.x + 1];
        float2 e = g2[3 * threadIdx.x + 2];
        float t20 = fmaf(a.x, a.x, fmaf(a.y, a.y, c.x * c.x));
        float t21 = fmaf(c.y, c.y, fmaf(e.x, e.x, e.y * e.y));
        s[2 * threadIdx.x + 0] = make_float4(a.x, a.y, c.x, t20);
        s[2 * threadIdx.x + 1] = make_float4(c.y, e.x, e.y, t21);
    }
    __syncthreads();

    const float* q = qbase + ((size_t)b * NPTS + qi) * 3;
    const float qx = q[0], qy = q[1], qz = q[2];
    const float q2 = fmaf(qx, qx, fmaf(qy, qy, qz * qz));
    const float nx = -2.f * qx, ny = -2.f * qy, nz = -2.f * qz;

    if (type < 2) {
        // 4 independent running mins -> no serial min chain
        float ma = FLT_MAX, mb = FLT_MAX, mc = FLT_MAX, md = FLT_MAX;
        #pragma unroll 4
        for (int j = 0; j < TPTS; j += 4) {
            float4 t0 = s[j + 0], t1 = s[j + 1], t2 = s[j + 2], t3 = s[j + 3];
            ma = fminf(ma, fmaf(nx, t0.x, fmaf(ny, t0.y, fmaf(nz, t0.z, t0.w))));
            mb = fminf(mb, fmaf(nx, t1.x, fmaf(ny, t1.y, fmaf(nz, t1.z, t1.w))));
            mc = fminf(mc, fmaf(nx, t2.x, fmaf(ny, t2.y, fmaf(nz, t2.z, t2.w))));
            md = fminf(md, fmaf(nx, t3.x, fmaf(ny, t3.y, fmaf(nz, t3.z, t3.w))));
        }
        float m = fminf(fminf(ma, mb), fminf(mc, md));
        minseg[(size_t)seg * NCH + (type * BATCH + b) * NPTS + qi] = m + q2;
    } else {
        float m0 = FLT_MAX, m1 = FLT_MAX, m2 = FLT_MAX, m3 = FLT_MAX;
        const int base = seg * TPTS;
        #pragma unroll 4
        for (int j = 0; j < TPTS; ++j) {
            float4 t = s[j];
            float h = fmaf(nx, t.x, fmaf(ny, t.y, fmaf(nz, t.z, t.w)));
            h = (base + j == qi) ? FLT_MAX : h;            // exclude self
            float n0 = fminf(m0, h);  float u0 = fmaxf(m0, h);
            float n1 = fminf(m1, u0); float u1 = fmaxf(m1, u0);
            float n2 = fminf(m2, u1); float u2 = fmaxf(m2, u1);
            float n3 = fminf(m3, u2);
            m0 = n0; m1 = n1; m2 = n2; m3 = n3;
        }
        // +q2 here so the merge kernel needs no input access (FLT_MAX+q2 -> inf, harmless)
        top4[(size_t)seg * NQ + b * NPTS + qi] =
            make_float4(m0 + q2, m1 + q2, m2 + q2, m3 + q2);
    }
}

// 192 blocks: [0,128) chamfer sum; [128,192) repulsion merge+eval.
// Last block (fenced atomic counter) finalizes both outputs.
__global__ __launch_bounds__(BLK) void merge_kernel(
    const float* __restrict__ minseg, const float4* __restrict__ top4,
    unsigned int* __restrict__ hdr, float* __restrict__ out)
{
    __shared__ float warr[BLK / 64];
    float contrib;
    int which;
    if (blockIdx.x < NCH / BLK) {
        int i = blockIdx.x * BLK + threadIdx.x;            // [0, 32768)
        float m = minseg[i];
        #pragma unroll
        for (int sg = 1; sg < SEG; ++sg)
            m = fminf(m, minseg[(size_t)sg * NCH + i]);
        contrib = fmaxf(m, 0.f);                           // clamp as in reference
        which = 0;
    } else {
        int i = (blockIdx.x - NCH / BLK) * BLK + threadIdx.x;  // [0, 16384)
        float m0 = FLT_MAX, m1 = FLT_MAX, m2 = FLT_MAX, m3 = FLT_MAX;
        #pragma unroll
        for (int sg = 0; sg < SEG; ++sg) {
            float4 v = top4[(size_t)sg * NQ + i];
            const float vals[4] = {v.x, v.y, v.z, v.w};
            #pragma unroll
            for (int k = 0; k < 4; ++k) {
                float h = vals[k];
                float n0 = fminf(m0, h);  float u0 = fmaxf(m0, h);
                float n1 = fminf(m1, u0); float u1 = fmaxf(m1, u0);
                float n2 = fminf(m2, u1); float u2 = fmaxf(m2, u1);
                float n3 = fminf(m3, u2);
                m0 = n0; m1 = n1; m2 = n2; m3 = n3;
            }
        }
        contrib = 0.f;
        const float ms[4] = {m0, m1, m2, m3};
        #pragma unroll
        for (int k = 0; k < 4; ++k) {
            float d2 = fmaxf(ms[k], EPS_C);
            float d  = sqrtf(d2);
            contrib += (RADIUS_C - d) * expf(-d2 * (1.f / H2));
        }
        which = 1;
    }
    #pragma unroll
    for (int off = 32; off > 0; off >>= 1)
        contrib += __shfl_down(contrib, off, 64);
    if ((threadIdx.x & 63) == 0) warr[threadIdx.x >> 6] = contrib;
    __syncthreads();
    if (threadIdx.x == 0) {
        float bs = warr[0] + warr[1] + warr[2] + warr[3];
        float* accum = (float*)hdr;
        atomicAdd(&accum[which], bs);
        __threadfence();
        unsigned int old = atomicAdd(&hdr[2], 1u);
        if (old == 191u) {                                  // last block: finalize
            float a0 = atomicAdd(&accum[0], 0.f);           // coherent read
            float a1 = atomicAdd(&accum[1], 0.f);
            out[0] = 100.f * a0 * (1.f / NQ);
            out[1] = a1 * (1.f / (NQ * 4));
        }
    }
}

extern "C" void kernel_launch(void* const* d_in, const int* in_sizes, int n_in,
                              void* d_out, int out_size, void* d_ws, size_t ws_size,
                              hipStream_t stream)
{
    const float* pred = (const float*)d_in[0];
    const float* gt   = (const float*)d_in[1];

    unsigned int* hdr    = (unsigned int*)d_ws;
    float*        minseg = (float*)((char*)d_ws + 16);
    float4*       top4   = (float4*)((char*)d_ws + 16 + (size_t)SEG * NCH * sizeof(float));

    dim3 grid(NPTS / BLK, SEG, 3 * BATCH);   // 16 x 8 x 12 = 1536 blocks
    partial_kernel<<<grid, BLK, 0, stream>>>(pred, gt, minseg, top4, hdr);
    merge_kernel<<<192, BLK, 0, stream>>>(minseg, top4, hdr, (float*)d_out);
}